// Round 1
// baseline (724.300 us; speedup 1.0000x reference)
//
#include <hip/hip_runtime.h>

// Row gather: out[i, :] = embedding[index[i], :]
// U = 1048576 rows, D = 64 floats/row (256 B), N = 2097152 lookups.
// One thread per float4 => 16 threads cooperate on one row.
// gid >> 4 = row, gid & 15 = float4 slot within row.
__global__ __launch_bounds__(256) void gather_rows_f32(
    const float4* __restrict__ emb,   // [U * 16] float4
    const int*    __restrict__ index, // [N]
    float4*       __restrict__ out,   // [N * 16] float4
    int n_float4)                     // N * 16
{
    int gid = blockIdx.x * blockDim.x + threadIdx.x;
    if (gid >= n_float4) return;

    int row  = gid >> 4;   // which lookup id
    int quad = gid & 15;   // which float4 within the 64-float row

    // 16 consecutive lanes read the same index -> L1 broadcast.
    int idx = index[row];

    // Row base in float4 units; keep address math in 64-bit to be safe
    // (byte offsets reach 268 MB for emb, 536 MB for out).
    size_t src = (size_t)idx * 16 + quad;
    out[gid] = emb[src];
}

extern "C" void kernel_launch(void* const* d_in, const int* in_sizes, int n_in,
                              void* d_out, int out_size, void* d_ws, size_t ws_size,
                              hipStream_t stream) {
    const float4* emb   = (const float4*)d_in[0];  // embedding [U*D] f32
    const int*    index = (const int*)d_in[1];     // index [N] i32
    float4*       out   = (float4*)d_out;          // [N*D] f32

    int n       = in_sizes[1];        // N lookups
    int n_f4    = n * 16;             // total float4 elements (N * D/4)
    int block   = 256;
    int grid    = (n_f4 + block - 1) / block;

    gather_rows_f32<<<grid, block, 0, stream>>>(emb, index, out, n_f4);
}